// Round 1
// baseline (143.892 us; speedup 1.0000x reference)
//
#include <hip/hip_runtime.h>
#include <math.h>

#define BINS 128

// ---------------- ws layout (float units) ----------------
// [0, 8192)        p        (B=2, C=64, 4,4,4) pooled means
// [8192, 8320)     s        (2, 64) sigmoid gate at 4x4x4
// [8320, 8384)     lo table (int[64])
// [8384, 8448)     w  table (float[64])
// [8448, 8450)     minmax mapped uints {min, max}
// [8456, 8584)     hist (uint[128])
// [8704, 8704+524288) s_up  (2, 64,64,64)

__device__ __forceinline__ unsigned mapf(float f) {
    unsigned u = __float_as_uint(f);
    return (u & 0x80000000u) ? ~u : (u | 0x80000000u);
}
__device__ __forceinline__ float unmapf(unsigned m) {
    unsigned u = (m & 0x80000000u) ? (m & 0x7FFFFFFFu) : ~m;
    return __uint_as_float(u);
}

// ---- Kernel A: adaptive avg pool 16^3 block means ----
// grid = 512 blocks: blk = (b*64+c)*4 + pd ; each block does a 16x64x64 slab
__global__ __launch_bounds__(256) void pool_kernel(const float* __restrict__ x,
                                                   float* __restrict__ p) {
    const int blk = blockIdx.x;
    const int t = threadIdx.x;
    const float4* xb = (const float4*)x + (size_t)blk * 16384;

    float acc0 = 0.f, acc1 = 0.f, acc2 = 0.f, acc3 = 0.f;
    // float4 index f = n*256 + t ;  ph = n&3 ; pw = (t&15)>>2  (derivation in notes)
    for (int n = 0; n < 64; n += 4) {
        float4 v0 = xb[(n + 0) * 256 + t]; acc0 += (v0.x + v0.y) + (v0.z + v0.w);
        float4 v1 = xb[(n + 1) * 256 + t]; acc1 += (v1.x + v1.y) + (v1.z + v1.w);
        float4 v2 = xb[(n + 2) * 256 + t]; acc2 += (v2.x + v2.y) + (v2.z + v2.w);
        float4 v3 = xb[(n + 3) * 256 + t]; acc3 += (v3.x + v3.y) + (v3.z + v3.w);
    }
    // reduce across lanes sharing pw: classes defined by lane bits {2,3}; xor over {1,2,16,32}
    #pragma unroll
    for (int m = 0; m < 4; ++m) {
        int mask = (m == 0) ? 1 : (m == 1) ? 2 : (m == 2) ? 16 : 32;
        acc0 += __shfl_xor(acc0, mask);
        acc1 += __shfl_xor(acc1, mask);
        acc2 += __shfl_xor(acc2, mask);
        acc3 += __shfl_xor(acc3, mask);
    }
    __shared__ float red[16 * 4];  // [cell=ph*4+pw][wave]
    const int lane = t & 63;
    const int wave = t >> 6;
    if (lane < 16 && (lane & 3) == 0) {
        const int pw = lane >> 2;
        red[(0 * 4 + pw) * 4 + wave] = acc0;
        red[(1 * 4 + pw) * 4 + wave] = acc1;
        red[(2 * 4 + pw) * 4 + wave] = acc2;
        red[(3 * 4 + pw) * 4 + wave] = acc3;
    }
    __syncthreads();
    if (t < 16) {
        float sum = red[t * 4 + 0] + red[t * 4 + 1] + red[t * 4 + 2] + red[t * 4 + 3];
        p[blk * 16 + t] = sum * (1.0f / 4096.0f);
    }
}

// ---- Kernel B: w1 conv + InstanceNorm + GELU + w2 conv + sigmoid + tables + init ----
__global__ __launch_bounds__(1024) void mid_kernel(const float* __restrict__ p,
                                                   const float* __restrict__ w1,
                                                   const float* __restrict__ w2,
                                                   float* __restrict__ s_out,
                                                   int* __restrict__ lo_tab,
                                                   float* __restrict__ w_tab,
                                                   unsigned* __restrict__ mm,
                                                   unsigned* __restrict__ hist) {
    __shared__ float hs[2 * 8 * 64];
    const int t = threadIdx.x;
    const int b = t >> 9, cm = (t >> 6) & 7, sp = t & 63;

    float h = 0.f;
    const float* pb = p + b * 64 * 64 + sp;
    const float* w1r = w1 + cm * 64;
    for (int c = 0; c < 64; ++c) h += w1r[c] * pb[c * 64];

    // each wave == one (b, cm) instance across its 64 spatial positions
    float s1 = h;
    #pragma unroll
    for (int m = 1; m <= 32; m <<= 1) s1 += __shfl_xor(s1, m);
    const float mu = s1 * (1.0f / 64.0f);
    float d = h - mu;
    float s2 = d * d;
    #pragma unroll
    for (int m = 1; m <= 32; m <<= 1) s2 += __shfl_xor(s2, m);
    const float var = s2 * (1.0f / 64.0f);
    const float hn = d / sqrtf(var + 1e-5f);
    const float g = 0.5f * hn * (1.0f + erff(hn * 0.70710678118654752440f));
    hs[(b * 8 + cm) * 64 + sp] = g;
    __syncthreads();

    if (t < 128) {
        const int bb = t >> 6, ss = t & 63;
        float acc = 0.f;
        #pragma unroll
        for (int c = 0; c < 8; ++c) acc += w2[c] * hs[(bb * 8 + c) * 64 + ss];
        s_out[t] = 1.0f / (1.0f + expf(-acc));
    }
    if (t < 64) {
        float coord = ((float)t + 0.5f) * 0.0625f - 0.5f;
        coord = fminf(fmaxf(coord, 0.0f), 3.0f);
        int lo = (int)floorf(coord);
        lo_tab[t] = lo;
        w_tab[t] = coord - (float)lo;
    }
    if (t == 0) { mm[0] = 0xFFFFFFFFu; mm[1] = 0u; }
    if (t >= 128 && t < 256) hist[t - 128] = 0u;
}

// ---- Kernel B2: trilinear upsample 4^3 -> 64^3 (per batch) ----
__global__ __launch_bounds__(256) void upsample_kernel(const float* __restrict__ s,
                                                       const int* __restrict__ lo_tab,
                                                       const float* __restrict__ w_tab,
                                                       float* __restrict__ s_up) {
    __shared__ float ls[128];
    __shared__ int llo[64];
    __shared__ float lwt[64];
    const int t = threadIdx.x;
    if (t < 128) ls[t] = s[t];
    if (t < 64) { llo[t] = lo_tab[t]; lwt[t] = w_tab[t]; }
    __syncthreads();

    for (int i = blockIdx.x * 256 + t; i < 2 * 262144; i += gridDim.x * 256) {
        const int wi = i & 63, hi = (i >> 6) & 63, di = (i >> 12) & 63, b = i >> 18;
        const int dl = llo[di], hl = llo[hi], wl = llo[wi];
        const int dh = min(dl + 1, 3), hh = min(hl + 1, 3), wh = min(wl + 1, 3);
        const float fd = lwt[di], fh = lwt[hi], fw = lwt[wi];
        const float* sb = ls + b * 64;
        float c00 = sb[dl * 16 + hl * 4 + wl] * (1.f - fw) + sb[dl * 16 + hl * 4 + wh] * fw;
        float c01 = sb[dl * 16 + hh * 4 + wl] * (1.f - fw) + sb[dl * 16 + hh * 4 + wh] * fw;
        float c10 = sb[dh * 16 + hl * 4 + wl] * (1.f - fw) + sb[dh * 16 + hl * 4 + wh] * fw;
        float c11 = sb[dh * 16 + hh * 4 + wl] * (1.f - fw) + sb[dh * 16 + hh * 4 + wh] * fw;
        float c0 = c00 * (1.f - fh) + c01 * fh;
        float c1 = c10 * (1.f - fh) + c11 * fh;
        s_up[i] = c0 * (1.f - fd) + c1 * fd;
    }
}

// ---- Kernel C: global min/max of x * s_up ----
__global__ __launch_bounds__(256) void minmax_kernel(const float* __restrict__ x,
                                                     const float* __restrict__ s_up,
                                                     unsigned* __restrict__ mm) {
    const float4* x4 = (const float4*)x;
    const float4* s4 = (const float4*)s_up;
    const int t = threadIdx.x;
    float vmin = INFINITY, vmax = -INFINITY;
    for (int i = blockIdx.x * 256 + t; i < 8388608; i += gridDim.x * 256) {
        float4 xv = x4[i];
        const int b = i >> 22;              // 2^22 float4 per batch
        float4 sv = s4[b * 65536 + (i & 65535)];
        float p0 = xv.x * sv.x, p1 = xv.y * sv.y, p2 = xv.z * sv.z, p3 = xv.w * sv.w;
        vmin = fminf(vmin, fminf(fminf(p0, p1), fminf(p2, p3)));
        vmax = fmaxf(vmax, fmaxf(fmaxf(p0, p1), fmaxf(p2, p3)));
    }
    #pragma unroll
    for (int m = 1; m <= 32; m <<= 1) {
        vmin = fminf(vmin, __shfl_xor(vmin, m));
        vmax = fmaxf(vmax, __shfl_xor(vmax, m));
    }
    __shared__ float smin[4], smax[4];
    const int wave = t >> 6;
    if ((t & 63) == 0) { smin[wave] = vmin; smax[wave] = vmax; }
    __syncthreads();
    if (t == 0) {
        float m0 = fminf(fminf(smin[0], smin[1]), fminf(smin[2], smin[3]));
        float M0 = fmaxf(fmaxf(smax[0], smax[1]), fmaxf(smax[2], smax[3]));
        atomicMin(&mm[0], mapf(m0));
        atomicMax(&mm[1], mapf(M0));
    }
}

// ---- Kernel D: 128-bin histogram of normalized x * s_up ----
__global__ __launch_bounds__(256) void hist_kernel(const float* __restrict__ x,
                                                   const float* __restrict__ s_up,
                                                   const unsigned* __restrict__ mm,
                                                   unsigned* __restrict__ ghist) {
    __shared__ unsigned lh[BINS];
    const int t = threadIdx.x;
    if (t < BINS) lh[t] = 0u;
    __syncthreads();

    const float vmin = unmapf(mm[0]);
    const float vmax = unmapf(mm[1]);
    const float inv = 128.0f / (vmax - vmin + 1e-8f);

    const float4* x4 = (const float4*)x;
    const float4* s4 = (const float4*)s_up;
    for (int i = blockIdx.x * 256 + t; i < 8388608; i += gridDim.x * 256) {
        float4 xv = x4[i];
        const int b = i >> 22;
        float4 sv = s4[b * 65536 + (i & 65535)];
        float p0 = xv.x * sv.x, p1 = xv.y * sv.y, p2 = xv.z * sv.z, p3 = xv.w * sv.w;
        int i0 = (int)floorf((p0 - vmin) * inv);
        int i1 = (int)floorf((p1 - vmin) * inv);
        int i2 = (int)floorf((p2 - vmin) * inv);
        int i3 = (int)floorf((p3 - vmin) * inv);
        i0 = min(max(i0, 0), BINS - 1);
        i1 = min(max(i1, 0), BINS - 1);
        i2 = min(max(i2, 0), BINS - 1);
        i3 = min(max(i3, 0), BINS - 1);
        atomicAdd(&lh[i0], 1u);
        atomicAdd(&lh[i1], 1u);
        atomicAdd(&lh[i2], 1u);
        atomicAdd(&lh[i3], 1u);
    }
    __syncthreads();
    if (t < BINS) {
        unsigned c = lh[t];
        if (c) atomicAdd(&ghist[t], c);
    }
}

// ---- Kernel E: entropy ----
__global__ __launch_bounds__(64) void entropy_kernel(const unsigned* __restrict__ ghist,
                                                     float* __restrict__ out) {
    const int t = threadIdx.x;
    float c0 = (float)ghist[t];
    float c1 = (float)ghist[t + 64];
    float s = c0 + c1;
    #pragma unroll
    for (int m = 1; m <= 32; m <<= 1) s += __shfl_xor(s, m);
    const float inv = 1.0f / (s + 1e-10f);
    float p0 = c0 * inv, p1 = c1 * inv;
    float e = p0 * log2f(p0 + 1e-10f) + p1 * log2f(p1 + 1e-10f);
    #pragma unroll
    for (int m = 1; m <= 32; m <<= 1) e += __shfl_xor(e, m);
    if (t == 0) out[0] = -e;
}

extern "C" void kernel_launch(void* const* d_in, const int* in_sizes, int n_in,
                              void* d_out, int out_size, void* d_ws, size_t ws_size,
                              hipStream_t stream) {
    (void)in_sizes; (void)n_in; (void)out_size; (void)ws_size;
    const float* x  = (const float*)d_in[0];
    const float* w1 = (const float*)d_in[1];
    const float* w2 = (const float*)d_in[2];

    float* ws = (float*)d_ws;
    float* p        = ws;                    // 8192
    float* s        = ws + 8192;             // 128
    int*   lo_tab   = (int*)(ws + 8320);     // 64
    float* w_tab    = ws + 8384;             // 64
    unsigned* mm    = (unsigned*)(ws + 8448);// 2
    unsigned* hist  = (unsigned*)(ws + 8456);// 128
    float* s_up     = ws + 8704;             // 524288

    pool_kernel<<<512, 256, 0, stream>>>(x, p);
    mid_kernel<<<1, 1024, 0, stream>>>(p, w1, w2, s, lo_tab, w_tab, mm, hist);
    upsample_kernel<<<512, 256, 0, stream>>>(s, lo_tab, w_tab, s_up);
    minmax_kernel<<<2048, 256, 0, stream>>>(x, s_up, mm);
    hist_kernel<<<1024, 256, 0, stream>>>(x, s_up, mm, hist);
    entropy_kernel<<<1, 64, 0, stream>>>(hist, (float*)d_out);
}